// Round 1
// baseline (5056.552 us; speedup 1.0000x reference)
//
#include <hip/hip_runtime.h>
#include <math.h>

#define NEG_SLOPE 0.3f
#define BN_EPS 1e-5f

static __device__ __forceinline__ float lrelu(float v) {
  return v >= 0.0f ? v : NEG_SLOPE * v;
}

static __device__ __forceinline__ int lower_bound_i(const int* __restrict__ a, int n, int v) {
  int lo = 0, hi = n;
  while (lo < hi) {
    int mid = (lo + hi) >> 1;
    if (a[mid] < v) lo = mid + 1; else hi = mid;
  }
  return lo;
}

// ---------------- init ----------------
__global__ void zero2_kernel(int* __restrict__ a, int* __restrict__ b, int n) {
  int i = blockIdx.x * blockDim.x + threadIdx.x;
  if (i < n) { a[i] = 0; b[i] = 0; }
}

// ---------------- CSR build ----------------
__global__ void hist_kernel(const int* __restrict__ dst, int ne, int* __restrict__ deg) {
  int i = blockIdx.x * blockDim.x + threadIdx.x;
  int stride = gridDim.x * blockDim.x;
  for (; i < ne; i += stride) atomicAdd(&deg[dst[i]], 1);
}

__global__ __launch_bounds__(1024) void scan_kernel(const int* __restrict__ deg,
    int* __restrict__ offs, int n) {
  __shared__ int part[1024];
  int t = threadIdx.x;
  int chunk = (n + 1023) >> 10;
  int s0 = t * chunk;
  int s1 = min(n, s0 + chunk);
  int sum = 0;
  for (int i = s0; i < s1; ++i) sum += deg[i];
  part[t] = sum;
  __syncthreads();
  for (int off = 1; off < 1024; off <<= 1) {
    int v = (t >= off) ? part[t - off] : 0;
    __syncthreads();
    part[t] += v;
    __syncthreads();
  }
  int run = (t > 0) ? part[t - 1] : 0;
  for (int i = s0; i < s1; ++i) { offs[i] = run; run += deg[i]; }
}

__global__ void scatter_kernel(const int* __restrict__ src, const int* __restrict__ dst,
    int ne, const int* __restrict__ offs, int* __restrict__ cursor,
    int* __restrict__ csr_src) {
  int i = blockIdx.x * blockDim.x + threadIdx.x;
  int stride = gridDim.x * blockDim.x;
  for (; i < ne; i += stride) {
    int d = dst[i];
    int pos = offs[d] + atomicAdd(&cursor[d], 1);
    csr_src[pos] = src[i];
  }
}

// ---------------- GEMM: C[n,128] = A[n,128] @ W[128,128] (fp32) ----------------
// X tile in LDS (8 KB), W streamed through L1/L2 (64 KB, reused per tile).
__global__ __launch_bounds__(256) void gemm128(const float* __restrict__ A,
    const float* __restrict__ W, float* __restrict__ C, int n) {
  __shared__ float Xr[16 * 128];
  int t = threadIdx.x;
  int tj = t & 127;   // output column
  int tr = t >> 7;    // 0 or 1: row parity
  int ntiles = (n + 15) >> 4;
  for (int tile = blockIdx.x; tile < ntiles; tile += gridDim.x) {
    int r0 = tile << 4;
    __syncthreads();
    for (int i = t; i < 16 * 128; i += 256) {
      int rr = i >> 7, cc = i & 127;
      int gr = r0 + rr;
      Xr[i] = (gr < n) ? A[(size_t)gr * 128 + cc] : 0.f;
    }
    __syncthreads();
    float acc[8] = {0.f, 0.f, 0.f, 0.f, 0.f, 0.f, 0.f, 0.f};
    for (int k = 0; k < 128; k += 4) {
      float4 xv[8];
#pragma unroll
      for (int rr = 0; rr < 8; rr++)
        xv[rr] = *(const float4*)&Xr[(tr + 2 * rr) * 128 + k];
#pragma unroll
      for (int kk = 0; kk < 4; kk++) {
        float w = W[(k + kk) * 128 + tj];
#pragma unroll
        for (int rr = 0; rr < 8; rr++) {
          float xs = (kk == 0) ? xv[rr].x : (kk == 1) ? xv[rr].y
                    : (kk == 2) ? xv[rr].z : xv[rr].w;
          acc[rr] += xs * w;
        }
      }
    }
#pragma unroll
    for (int rr = 0; rr < 8; rr++) {
      int gr = r0 + tr + 2 * rr;
      if (gr < n) C[(size_t)gr * 128 + tj] = acc[rr];
    }
  }
}

// ---------------- GATv2 layer 1: scores (8 heads x 16 ch), one wave per node ----
__global__ __launch_bounds__(64) void score1_kernel(const float* __restrict__ xl,
    const float* __restrict__ xr, const int* __restrict__ csr_src,
    const int* __restrict__ offs, const int* __restrict__ deg,
    const float* __restrict__ att, float* __restrict__ scores,
    float* __restrict__ mx, int n_nodes) {
  int n = blockIdx.x;
  if (n >= n_nodes) return;
  int l = threadIdx.x;
  int base = offs[n], d = deg[n];
  float2 xrv = *(const float2*)&xr[(size_t)n * 128 + 2 * l];
  float a0 = att[2 * l], a1 = att[2 * l + 1];
  float m = -__builtin_inff();
  for (int i = 0; i < d; ++i) {
    int s = csr_src[base + i];
    float2 xlv = *(const float2*)&xl[(size_t)s * 128 + 2 * l];
    float p = lrelu(xlv.x + xrv.x) * a0 + lrelu(xlv.y + xrv.y) * a1;
    // reduce within each 8-lane head group (16 ch / head, 2 ch / lane)
    p += __shfl_xor(p, 1);
    p += __shfl_xor(p, 2);
    p += __shfl_xor(p, 4);
    m = fmaxf(m, p);
    if ((l & 7) == 0) scores[(size_t)(base + i) * 8 + (l >> 3)] = p;
  }
  if ((l & 7) == 0) mx[n * 8 + (l >> 3)] = m;
}

// ---------------- GATv2 layer 1: softmax-normalize + aggregate + bias/BN/ReLU ---
__global__ __launch_bounds__(64) void agg1_kernel(const float* __restrict__ xl,
    const int* __restrict__ csr_src, const int* __restrict__ offs,
    const int* __restrict__ deg, const float* __restrict__ scores,
    const float* __restrict__ mx, const float* __restrict__ bias,
    const float* __restrict__ bn_g, const float* __restrict__ bn_b,
    const float* __restrict__ bn_rm, const float* __restrict__ bn_rv,
    float* __restrict__ out, int n_nodes) {
  int n = blockIdx.x;
  if (n >= n_nodes) return;
  int l = threadIdx.x;
  int base = offs[n], d = deg[n];
  float m = mx[n * 8 + (l >> 3)];
  float ssum = 0.f, ax = 0.f, ay = 0.f;
  for (int i = 0; i < d; ++i) {
    int e = base + i;
    float sc = scores[(size_t)e * 8 + (l >> 3)];
    int s = csr_src[e];
    float ex = expf(sc - m);
    float2 xlv = *(const float2*)&xl[(size_t)s * 128 + 2 * l];
    ssum += ex;
    ax += ex * xlv.x;
    ay += ex * xlv.y;
  }
  float inv = 1.f / (ssum + 1e-16f);
  int c0 = 2 * l, c1 = 2 * l + 1;
  float o0 = ax * inv + bias[c0];
  float o1 = ay * inv + bias[c1];
  float sc0 = bn_g[c0] / sqrtf(bn_rv[c0] + BN_EPS);
  float sc1 = bn_g[c1] / sqrtf(bn_rv[c1] + BN_EPS);
  o0 = fmaxf((o0 - bn_rm[c0]) * sc0 + bn_b[c0], 0.f);
  o1 = fmaxf((o1 - bn_rm[c1]) * sc1 + bn_b[c1], 0.f);
  *(float2*)&out[(size_t)n * 128 + 2 * l] = make_float2(o0, o1);
}

// ---------------- GATv2 layer 2: scores (1 head x 128 ch) ----------------
__global__ __launch_bounds__(64) void score2_kernel(const float* __restrict__ xl,
    const float* __restrict__ xr, const int* __restrict__ csr_src,
    const int* __restrict__ offs, const int* __restrict__ deg,
    const float* __restrict__ att, float* __restrict__ scores,
    float* __restrict__ mx, int n_nodes) {
  int n = blockIdx.x;
  if (n >= n_nodes) return;
  int l = threadIdx.x;
  int base = offs[n], d = deg[n];
  float2 xrv = *(const float2*)&xr[(size_t)n * 128 + 2 * l];
  float a0 = att[2 * l], a1 = att[2 * l + 1];
  float m = -__builtin_inff();
  for (int i = 0; i < d; ++i) {
    int s = csr_src[base + i];
    float2 xlv = *(const float2*)&xl[(size_t)s * 128 + 2 * l];
    float p = lrelu(xlv.x + xrv.x) * a0 + lrelu(xlv.y + xrv.y) * a1;
    p += __shfl_xor(p, 1);
    p += __shfl_xor(p, 2);
    p += __shfl_xor(p, 4);
    p += __shfl_xor(p, 8);
    p += __shfl_xor(p, 16);
    p += __shfl_xor(p, 32);
    m = fmaxf(m, p);
    if (l == 0) scores[base + i] = p;
  }
  if (l == 0) mx[n] = m;
}

__global__ __launch_bounds__(64) void agg2_kernel(const float* __restrict__ xl,
    const int* __restrict__ csr_src, const int* __restrict__ offs,
    const int* __restrict__ deg, const float* __restrict__ scores,
    const float* __restrict__ mx, const float* __restrict__ bias,
    const float* __restrict__ bn_g, const float* __restrict__ bn_b,
    const float* __restrict__ bn_rm, const float* __restrict__ bn_rv,
    float* __restrict__ out, int n_nodes) {
  int n = blockIdx.x;
  if (n >= n_nodes) return;
  int l = threadIdx.x;
  int base = offs[n], d = deg[n];
  float m = mx[n];
  float ssum = 0.f, ax = 0.f, ay = 0.f;
  for (int i = 0; i < d; ++i) {
    int e = base + i;
    float sc = scores[e];
    int s = csr_src[e];
    float ex = expf(sc - m);
    float2 xlv = *(const float2*)&xl[(size_t)s * 128 + 2 * l];
    ssum += ex;
    ax += ex * xlv.x;
    ay += ex * xlv.y;
  }
  float inv = 1.f / (ssum + 1e-16f);
  int c0 = 2 * l, c1 = 2 * l + 1;
  float o0 = ax * inv + bias[c0];
  float o1 = ay * inv + bias[c1];
  float sc0 = bn_g[c0] / sqrtf(bn_rv[c0] + BN_EPS);
  float sc1 = bn_g[c1] / sqrtf(bn_rv[c1] + BN_EPS);
  o0 = fmaxf((o0 - bn_rm[c0]) * sc0 + bn_b[c0], 0.f);
  o1 = fmaxf((o1 - bn_rm[c1]) * sc1 + bn_b[c1], 0.f);
  *(float2*)&out[(size_t)n * 128 + 2 * l] = make_float2(o0, o1);
}

// ---------------- gate_nn: gate[n] = tanh(h2 @ Wg1 + bg1) . Wg2 ----------------
__global__ __launch_bounds__(128) void gate_kernel(const float* __restrict__ h2,
    const float* __restrict__ Wg1, const float* __restrict__ bg1,
    const float* __restrict__ Wg2, float* __restrict__ gate, int n) {
  __shared__ float Xr[8 * 128];
  __shared__ float red[8 * 128];
  int t = threadIdx.x;
  float bg = bg1[t], w2 = Wg2[t];
  int ntiles = (n + 7) >> 3;
  for (int tile = blockIdx.x; tile < ntiles; tile += gridDim.x) {
    int r0 = tile << 3;
    __syncthreads();
    for (int i = t; i < 8 * 128; i += 128) {
      int rr = i >> 7, cc = i & 127;
      int gr = r0 + rr;
      Xr[i] = (gr < n) ? h2[(size_t)gr * 128 + cc] : 0.f;
    }
    __syncthreads();
    float acc[8] = {bg, bg, bg, bg, bg, bg, bg, bg};
    for (int k = 0; k < 128; k += 4) {
      float4 xv[8];
#pragma unroll
      for (int rr = 0; rr < 8; rr++)
        xv[rr] = *(const float4*)&Xr[rr * 128 + k];
#pragma unroll
      for (int kk = 0; kk < 4; kk++) {
        float w = Wg1[(k + kk) * 128 + t];
#pragma unroll
        for (int rr = 0; rr < 8; rr++) {
          float xs = (kk == 0) ? xv[rr].x : (kk == 1) ? xv[rr].y
                    : (kk == 2) ? xv[rr].z : xv[rr].w;
          acc[rr] += xs * w;
        }
      }
    }
#pragma unroll
    for (int rr = 0; rr < 8; rr++) red[rr * 128 + t] = tanhf(acc[rr]) * w2;
    __syncthreads();
    for (int off = 64; off >= 1; off >>= 1) {
      if (t < off) {
#pragma unroll
        for (int rr = 0; rr < 8; rr++) red[rr * 128 + t] += red[rr * 128 + t + off];
      }
      __syncthreads();
    }
    if (t < 8) {
      int gr = r0 + t;
      if (gr < n) gate[gr] = red[t * 128];
    }
  }
}

// ---------------- attentional pooling per graph ----------------
__global__ __launch_bounds__(128) void pool_kernel(const float* __restrict__ gate,
    const float* __restrict__ h2, const int* __restrict__ batch, int n_nodes,
    float* __restrict__ pooled, int n_graphs) {
  int g = blockIdx.x;
  if (g >= n_graphs) return;
  int t = threadIdx.x;
  int start = lower_bound_i(batch, n_nodes, g);
  int end = lower_bound_i(batch, n_nodes, g + 1);
  __shared__ float red[128];
  float m = -__builtin_inff();
  for (int i = start + t; i < end; i += 128) m = fmaxf(m, gate[i]);
  red[t] = m;
  __syncthreads();
  for (int off = 64; off >= 1; off >>= 1) {
    if (t < off) red[t] = fmaxf(red[t], red[t + off]);
    __syncthreads();
  }
  m = red[0];
  float s = 0.f, acc = 0.f;
  for (int i = start; i < end; ++i) {
    float ex = expf(gate[i] - m);
    s += ex;
    acc += ex * h2[(size_t)i * 128 + t];
  }
  pooled[(size_t)g * 128 + t] = acc / (s + 1e-16f);
}

// ---------------- fc head: out = relu(pooled @ Wf1 + bf1) @ Wf2 + bf2 ----------
__global__ __launch_bounds__(128) void fc_kernel(const float* __restrict__ pooled,
    const float* __restrict__ Wf1, const float* __restrict__ bf1,
    const float* __restrict__ Wf2, const float* __restrict__ bf2,
    float* __restrict__ out, int n_graphs) {
  int g = blockIdx.x;
  if (g >= n_graphs) return;
  int t = threadIdx.x;
  __shared__ float pl[128];
  __shared__ float red[128];
  pl[t] = pooled[(size_t)g * 128 + t];
  __syncthreads();
  float v = 0.f;
  if (t < 100) {
    float acc = bf1[t];
    for (int k = 0; k < 128; ++k) acc += pl[k] * Wf1[k * 100 + t];
    v = fmaxf(acc, 0.f) * Wf2[t];
  }
  red[t] = v;
  __syncthreads();
  for (int off = 64; off >= 1; off >>= 1) {
    if (t < off) red[t] += red[t + off];
    __syncthreads();
  }
  if (t == 0) out[g] = red[0] + bf2[0];
}

extern "C" void kernel_launch(void* const* d_in, const int* in_sizes, int n_in,
                              void* d_out, int out_size, void* d_ws, size_t ws_size,
                              hipStream_t stream) {
  const float* x     = (const float*)d_in[0];
  const int*   ei    = (const int*)d_in[1];
  const int*   batch = (const int*)d_in[2];
  const float* Wl1   = (const float*)d_in[3];
  const float* Wr1   = (const float*)d_in[4];
  const float* att1  = (const float*)d_in[5];
  const float* b1    = (const float*)d_in[6];
  const float* Wl2   = (const float*)d_in[7];
  const float* Wr2   = (const float*)d_in[8];
  const float* att2  = (const float*)d_in[9];
  const float* b2    = (const float*)d_in[10];
  const float* bn_g  = (const float*)d_in[11];
  const float* bn_b  = (const float*)d_in[12];
  const float* bn_rm = (const float*)d_in[13];
  const float* bn_rv = (const float*)d_in[14];
  const float* Wg1   = (const float*)d_in[15];
  const float* bg1   = (const float*)d_in[16];
  const float* Wg2   = (const float*)d_in[17];
  const float* Wf1   = (const float*)d_in[18];
  const float* bf1   = (const float*)d_in[19];
  const float* Wf2   = (const float*)d_in[20];
  const float* bf2   = (const float*)d_in[21];

  const int N  = in_sizes[0] / 128;
  const int E  = in_sizes[1] / 2;
  const int NG = out_size;
  const int* src = ei;
  const int* dst = ei + E;

  // ---- workspace arena (256B-aligned) ----
  char* p = (char*)d_ws;
  auto alloc = [&](size_t bytes) -> void* {
    void* r = (void*)p;
    p += (bytes + 255) & ~(size_t)255;
    return r;
  };
  float* bufA    = (float*)alloc((size_t)N * 128 * 4);  // xl1, later xl2
  float* bufB    = (float*)alloc((size_t)N * 128 * 4);  // xr1, later xr2
  float* h1      = (float*)alloc((size_t)N * 128 * 4);  // h1, later reused as h2
  float* scores  = (float*)alloc((size_t)E * 8 * 4);
  float* mx      = (float*)alloc((size_t)N * 8 * 4);
  int*   deg     = (int*)alloc((size_t)N * 4);
  int*   cursor  = (int*)alloc((size_t)N * 4);
  int*   offs    = (int*)alloc((size_t)N * 4);
  int*   csr_src = (int*)alloc((size_t)E * 4);
  float* gate    = (float*)alloc((size_t)N * 4);
  float* pooled  = (float*)alloc((size_t)NG * 128 * 4);
  float* h2      = h1;  // h1 dead after layer-2 GEMMs; safe alias (in-order stream)

  // ---- CSR build ----
  zero2_kernel<<<(N + 255) / 256, 256, 0, stream>>>(deg, cursor, N);
  hist_kernel<<<1024, 256, 0, stream>>>(dst, E, deg);
  scan_kernel<<<1, 1024, 0, stream>>>(deg, offs, N);
  scatter_kernel<<<1024, 256, 0, stream>>>(src, dst, E, offs, cursor, csr_src);

  // ---- layer 1 ----
  gemm128<<<1024, 256, 0, stream>>>(x, Wl1, bufA, N);
  gemm128<<<1024, 256, 0, stream>>>(x, Wr1, bufB, N);
  score1_kernel<<<N, 64, 0, stream>>>(bufA, bufB, csr_src, offs, deg, att1, scores, mx, N);
  agg1_kernel<<<N, 64, 0, stream>>>(bufA, csr_src, offs, deg, scores, mx, b1,
                                    bn_g, bn_b, bn_rm, bn_rv, h1, N);

  // ---- layer 2 ----
  gemm128<<<1024, 256, 0, stream>>>(h1, Wl2, bufA, N);
  gemm128<<<1024, 256, 0, stream>>>(h1, Wr2, bufB, N);
  score2_kernel<<<N, 64, 0, stream>>>(bufA, bufB, csr_src, offs, deg, att2, scores, mx, N);
  agg2_kernel<<<N, 64, 0, stream>>>(bufA, csr_src, offs, deg, scores, mx, b2,
                                    bn_g, bn_b, bn_rm, bn_rv, h2, N);

  // ---- pooling + head ----
  gate_kernel<<<1024, 128, 0, stream>>>(h2, Wg1, bg1, Wg2, gate, N);
  pool_kernel<<<NG, 128, 0, stream>>>(gate, h2, batch, N, pooled, NG);
  fc_kernel<<<NG, 128, 0, stream>>>(pooled, Wf1, bf1, Wf2, bf2, (float*)d_out, NG);
}

// Round 2
// 1144.698 us; speedup vs baseline: 4.4174x; 4.4174x over previous
//
#include <hip/hip_runtime.h>
#include <math.h>

#define NEG_SLOPE 0.3f
#define BN_EPS 1e-5f

static __device__ __forceinline__ float lrelu(float v) {
  return v >= 0.0f ? v : NEG_SLOPE * v;
}

static __device__ __forceinline__ int lower_bound_i(const int* __restrict__ a, int n, int v) {
  int lo = 0, hi = n;
  while (lo < hi) {
    int mid = (lo + hi) >> 1;
    if (a[mid] < v) lo = mid + 1; else hi = mid;
  }
  return lo;
}

// ---------------- init ----------------
__global__ void zero2_kernel(int* __restrict__ a, int* __restrict__ b, int n) {
  int i = blockIdx.x * blockDim.x + threadIdx.x;
  if (i < n) { a[i] = 0; b[i] = 0; }
}

// ---------------- CSR build ----------------
__global__ void hist_kernel(const int* __restrict__ dst, int ne, int* __restrict__ deg) {
  int i = blockIdx.x * blockDim.x + threadIdx.x;
  int stride = gridDim.x * blockDim.x;
  for (; i < ne; i += stride) atomicAdd(&deg[dst[i]], 1);
}

__global__ __launch_bounds__(1024) void scan_kernel(const int* __restrict__ deg,
    int* __restrict__ offs, int n) {
  __shared__ int part[1024];
  int t = threadIdx.x;
  int chunk = (n + 1023) >> 10;
  int s0 = t * chunk;
  int s1 = min(n, s0 + chunk);
  int sum = 0;
  for (int i = s0; i < s1; ++i) sum += deg[i];
  part[t] = sum;
  __syncthreads();
  for (int off = 1; off < 1024; off <<= 1) {
    int v = (t >= off) ? part[t - off] : 0;
    __syncthreads();
    part[t] += v;
    __syncthreads();
  }
  int run = (t > 0) ? part[t - 1] : 0;
  for (int i = s0; i < s1; ++i) { offs[i] = run; run += deg[i]; }
}

__global__ void scatter_kernel(const int* __restrict__ src, const int* __restrict__ dst,
    int ne, const int* __restrict__ offs, int* __restrict__ cursor,
    int* __restrict__ csr_src) {
  int i = blockIdx.x * blockDim.x + threadIdx.x;
  int stride = gridDim.x * blockDim.x;
  for (; i < ne; i += stride) {
    int d = dst[i];
    int pos = offs[d] + atomicAdd(&cursor[d], 1);
    csr_src[pos] = src[i];
  }
}

// ---------------- GEMM: C[n,128] = A[n,128] @ W[128,128] (fp32) ----------------
// W fully staged in LDS (64 KB). Block = 256 thr = 8 rowgroups x 32 colgroups.
// Tile = 64 rows x 128 cols; each thread: 8 rows x 4 cols = 32 accumulators.
// A read from global: per wave only 2 distinct 16B addresses per load (L1 broadcast).
// Register budget: 32 acc + 16 Wfrag + 4 Afrag + addr ~= 90 VGPR -> no spills.
__global__ __launch_bounds__(256) void gemm128(const float* __restrict__ A,
    const float* __restrict__ W, float* __restrict__ C, int n) {
  __shared__ float Wl[128 * 128];  // 64 KB
  int t = threadIdx.x;
  for (int i = t; i < 4096; i += 256)
    ((float4*)Wl)[i] = ((const float4*)W)[i];
  __syncthreads();
  int cg = t & 31;   // colgroup: owns cols 4*cg .. 4*cg+3
  int rg = t >> 5;   // rowgroup: owns 8 rows
  int ntiles = (n + 63) >> 6;
  for (int tile = blockIdx.x; tile < ntiles; tile += gridDim.x) {
    int r0 = (tile << 6) + rg * 8;
    const float* Ar[8];
#pragma unroll
    for (int r = 0; r < 8; ++r) {
      int gr = min(r0 + r, n - 1);          // clamp for loads; stores guarded
      Ar[r] = A + (size_t)gr * 128;
    }
    float4 acc[8];
#pragma unroll
    for (int r = 0; r < 8; ++r) acc[r] = make_float4(0.f, 0.f, 0.f, 0.f);
#pragma unroll 4
    for (int k = 0; k < 128; k += 4) {
      float4 w0 = *(const float4*)&Wl[(k + 0) * 128 + cg * 4];
      float4 w1 = *(const float4*)&Wl[(k + 1) * 128 + cg * 4];
      float4 w2 = *(const float4*)&Wl[(k + 2) * 128 + cg * 4];
      float4 w3 = *(const float4*)&Wl[(k + 3) * 128 + cg * 4];
#pragma unroll
      for (int r = 0; r < 8; ++r) {
        float4 av = *(const float4*)(Ar[r] + k);
        acc[r].x += av.x * w0.x + av.y * w1.x + av.z * w2.x + av.w * w3.x;
        acc[r].y += av.x * w0.y + av.y * w1.y + av.z * w2.y + av.w * w3.y;
        acc[r].z += av.x * w0.z + av.y * w1.z + av.z * w2.z + av.w * w3.z;
        acc[r].w += av.x * w0.w + av.y * w1.w + av.z * w2.w + av.w * w3.w;
      }
    }
#pragma unroll
    for (int r = 0; r < 8; ++r) {
      int gr = r0 + r;
      if (gr < n) *(float4*)&C[(size_t)gr * 128 + cg * 4] = acc[r];
    }
  }
}

// ---------------- gate: gate[n] = tanh(h2 @ Wg1 + bg1) . Wg2 -------------------
// Same skeleton as gemm128; epilogue does tanh + dot(Wg2) + 32-lane reduce.
__global__ __launch_bounds__(256) void gate_kernel(const float* __restrict__ A,
    const float* __restrict__ Wg1, const float* __restrict__ bg1,
    const float* __restrict__ Wg2, float* __restrict__ gate, int n) {
  __shared__ float Wl[128 * 128];  // 64 KB
  int t = threadIdx.x;
  for (int i = t; i < 4096; i += 256)
    ((float4*)Wl)[i] = ((const float4*)Wg1)[i];
  __syncthreads();
  int cg = t & 31;
  int rg = t >> 5;
  float4 bg4 = *(const float4*)&bg1[cg * 4];
  float4 wg4 = *(const float4*)&Wg2[cg * 4];
  int ntiles = (n + 63) >> 6;
  for (int tile = blockIdx.x; tile < ntiles; tile += gridDim.x) {
    int r0 = (tile << 6) + rg * 8;
    const float* Ar[8];
#pragma unroll
    for (int r = 0; r < 8; ++r) {
      int gr = min(r0 + r, n - 1);
      Ar[r] = A + (size_t)gr * 128;
    }
    float4 acc[8];
#pragma unroll
    for (int r = 0; r < 8; ++r) acc[r] = make_float4(0.f, 0.f, 0.f, 0.f);
#pragma unroll 4
    for (int k = 0; k < 128; k += 4) {
      float4 w0 = *(const float4*)&Wl[(k + 0) * 128 + cg * 4];
      float4 w1 = *(const float4*)&Wl[(k + 1) * 128 + cg * 4];
      float4 w2 = *(const float4*)&Wl[(k + 2) * 128 + cg * 4];
      float4 w3 = *(const float4*)&Wl[(k + 3) * 128 + cg * 4];
#pragma unroll
      for (int r = 0; r < 8; ++r) {
        float4 av = *(const float4*)(Ar[r] + k);
        acc[r].x += av.x * w0.x + av.y * w1.x + av.z * w2.x + av.w * w3.x;
        acc[r].y += av.x * w0.y + av.y * w1.y + av.z * w2.y + av.w * w3.y;
        acc[r].z += av.x * w0.z + av.y * w1.z + av.z * w2.z + av.w * w3.z;
        acc[r].w += av.x * w0.w + av.y * w1.w + av.z * w2.w + av.w * w3.w;
      }
    }
#pragma unroll
    for (int r = 0; r < 8; ++r) {
      float v = tanhf(acc[r].x + bg4.x) * wg4.x
              + tanhf(acc[r].y + bg4.y) * wg4.y
              + tanhf(acc[r].z + bg4.z) * wg4.z
              + tanhf(acc[r].w + bg4.w) * wg4.w;
      v += __shfl_xor(v, 1);
      v += __shfl_xor(v, 2);
      v += __shfl_xor(v, 4);
      v += __shfl_xor(v, 8);
      v += __shfl_xor(v, 16);
      int gr = r0 + r;
      if (cg == 0 && gr < n) gate[gr] = v;
    }
  }
}

// ---------------- GATv2 layer 1: scores (8 heads x 16 ch), one wave per node ----
__global__ __launch_bounds__(64) void score1_kernel(const float* __restrict__ xl,
    const float* __restrict__ xr, const int* __restrict__ csr_src,
    const int* __restrict__ offs, const int* __restrict__ deg,
    const float* __restrict__ att, float* __restrict__ scores,
    float* __restrict__ mx, int n_nodes) {
  int n = blockIdx.x;
  if (n >= n_nodes) return;
  int l = threadIdx.x;
  int base = offs[n], d = deg[n];
  float2 xrv = *(const float2*)&xr[(size_t)n * 128 + 2 * l];
  float a0 = att[2 * l], a1 = att[2 * l + 1];
  float m = -__builtin_inff();
  for (int i = 0; i < d; ++i) {
    int s = csr_src[base + i];
    float2 xlv = *(const float2*)&xl[(size_t)s * 128 + 2 * l];
    float p = lrelu(xlv.x + xrv.x) * a0 + lrelu(xlv.y + xrv.y) * a1;
    // reduce within each 8-lane head group (16 ch / head, 2 ch / lane)
    p += __shfl_xor(p, 1);
    p += __shfl_xor(p, 2);
    p += __shfl_xor(p, 4);
    m = fmaxf(m, p);
    if ((l & 7) == 0) scores[(size_t)(base + i) * 8 + (l >> 3)] = p;
  }
  if ((l & 7) == 0) mx[n * 8 + (l >> 3)] = m;
}

// ---------------- GATv2 layer 1: softmax-normalize + aggregate + bias/BN/ReLU ---
__global__ __launch_bounds__(64) void agg1_kernel(const float* __restrict__ xl,
    const int* __restrict__ csr_src, const int* __restrict__ offs,
    const int* __restrict__ deg, const float* __restrict__ scores,
    const float* __restrict__ mx, const float* __restrict__ bias,
    const float* __restrict__ bn_g, const float* __restrict__ bn_b,
    const float* __restrict__ bn_rm, const float* __restrict__ bn_rv,
    float* __restrict__ out, int n_nodes) {
  int n = blockIdx.x;
  if (n >= n_nodes) return;
  int l = threadIdx.x;
  int base = offs[n], d = deg[n];
  float m = mx[n * 8 + (l >> 3)];
  float ssum = 0.f, ax = 0.f, ay = 0.f;
  for (int i = 0; i < d; ++i) {
    int e = base + i;
    float sc = scores[(size_t)e * 8 + (l >> 3)];
    int s = csr_src[e];
    float ex = expf(sc - m);
    float2 xlv = *(const float2*)&xl[(size_t)s * 128 + 2 * l];
    ssum += ex;
    ax += ex * xlv.x;
    ay += ex * xlv.y;
  }
  float inv = 1.f / (ssum + 1e-16f);
  int c0 = 2 * l, c1 = 2 * l + 1;
  float o0 = ax * inv + bias[c0];
  float o1 = ay * inv + bias[c1];
  float sc0 = bn_g[c0] / sqrtf(bn_rv[c0] + BN_EPS);
  float sc1 = bn_g[c1] / sqrtf(bn_rv[c1] + BN_EPS);
  o0 = fmaxf((o0 - bn_rm[c0]) * sc0 + bn_b[c0], 0.f);
  o1 = fmaxf((o1 - bn_rm[c1]) * sc1 + bn_b[c1], 0.f);
  *(float2*)&out[(size_t)n * 128 + 2 * l] = make_float2(o0, o1);
}

// ---------------- GATv2 layer 2: scores (1 head x 128 ch) ----------------
__global__ __launch_bounds__(64) void score2_kernel(const float* __restrict__ xl,
    const float* __restrict__ xr, const int* __restrict__ csr_src,
    const int* __restrict__ offs, const int* __restrict__ deg,
    const float* __restrict__ att, float* __restrict__ scores,
    float* __restrict__ mx, int n_nodes) {
  int n = blockIdx.x;
  if (n >= n_nodes) return;
  int l = threadIdx.x;
  int base = offs[n], d = deg[n];
  float2 xrv = *(const float2*)&xr[(size_t)n * 128 + 2 * l];
  float a0 = att[2 * l], a1 = att[2 * l + 1];
  float m = -__builtin_inff();
  for (int i = 0; i < d; ++i) {
    int s = csr_src[base + i];
    float2 xlv = *(const float2*)&xl[(size_t)s * 128 + 2 * l];
    float p = lrelu(xlv.x + xrv.x) * a0 + lrelu(xlv.y + xrv.y) * a1;
    p += __shfl_xor(p, 1);
    p += __shfl_xor(p, 2);
    p += __shfl_xor(p, 4);
    p += __shfl_xor(p, 8);
    p += __shfl_xor(p, 16);
    p += __shfl_xor(p, 32);
    m = fmaxf(m, p);
    if (l == 0) scores[base + i] = p;
  }
  if (l == 0) mx[n] = m;
}

__global__ __launch_bounds__(64) void agg2_kernel(const float* __restrict__ xl,
    const int* __restrict__ csr_src, const int* __restrict__ offs,
    const int* __restrict__ deg, const float* __restrict__ scores,
    const float* __restrict__ mx, const float* __restrict__ bias,
    const float* __restrict__ bn_g, const float* __restrict__ bn_b,
    const float* __restrict__ bn_rm, const float* __restrict__ bn_rv,
    float* __restrict__ out, int n_nodes) {
  int n = blockIdx.x;
  if (n >= n_nodes) return;
  int l = threadIdx.x;
  int base = offs[n], d = deg[n];
  float m = mx[n];
  float ssum = 0.f, ax = 0.f, ay = 0.f;
  for (int i = 0; i < d; ++i) {
    int e = base + i;
    float sc = scores[e];
    int s = csr_src[e];
    float ex = expf(sc - m);
    float2 xlv = *(const float2*)&xl[(size_t)s * 128 + 2 * l];
    ssum += ex;
    ax += ex * xlv.x;
    ay += ex * xlv.y;
  }
  float inv = 1.f / (ssum + 1e-16f);
  int c0 = 2 * l, c1 = 2 * l + 1;
  float o0 = ax * inv + bias[c0];
  float o1 = ay * inv + bias[c1];
  float sc0 = bn_g[c0] / sqrtf(bn_rv[c0] + BN_EPS);
  float sc1 = bn_g[c1] / sqrtf(bn_rv[c1] + BN_EPS);
  o0 = fmaxf((o0 - bn_rm[c0]) * sc0 + bn_b[c0], 0.f);
  o1 = fmaxf((o1 - bn_rm[c1]) * sc1 + bn_b[c1], 0.f);
  *(float2*)&out[(size_t)n * 128 + 2 * l] = make_float2(o0, o1);
}

// ---------------- attentional pooling per graph ----------------
__global__ __launch_bounds__(128) void pool_kernel(const float* __restrict__ gate,
    const float* __restrict__ h2, const int* __restrict__ batch, int n_nodes,
    float* __restrict__ pooled, int n_graphs) {
  int g = blockIdx.x;
  if (g >= n_graphs) return;
  int t = threadIdx.x;
  int start = lower_bound_i(batch, n_nodes, g);
  int end = lower_bound_i(batch, n_nodes, g + 1);
  __shared__ float red[128];
  float m = -__builtin_inff();
  for (int i = start + t; i < end; i += 128) m = fmaxf(m, gate[i]);
  red[t] = m;
  __syncthreads();
  for (int off = 64; off >= 1; off >>= 1) {
    if (t < off) red[t] = fmaxf(red[t], red[t + off]);
    __syncthreads();
  }
  m = red[0];
  float s = 0.f, acc = 0.f;
  for (int i = start; i < end; ++i) {
    float ex = expf(gate[i] - m);
    s += ex;
    acc += ex * h2[(size_t)i * 128 + t];
  }
  pooled[(size_t)g * 128 + t] = acc / (s + 1e-16f);
}

// ---------------- fc head: out = relu(pooled @ Wf1 + bf1) @ Wf2 + bf2 ----------
__global__ __launch_bounds__(128) void fc_kernel(const float* __restrict__ pooled,
    const float* __restrict__ Wf1, const float* __restrict__ bf1,
    const float* __restrict__ Wf2, const float* __restrict__ bf2,
    float* __restrict__ out, int n_graphs) {
  int g = blockIdx.x;
  if (g >= n_graphs) return;
  int t = threadIdx.x;
  __shared__ float pl[128];
  __shared__ float red[128];
  pl[t] = pooled[(size_t)g * 128 + t];
  __syncthreads();
  float v = 0.f;
  if (t < 100) {
    float acc = bf1[t];
    for (int k = 0; k < 128; ++k) acc += pl[k] * Wf1[k * 100 + t];
    v = fmaxf(acc, 0.f) * Wf2[t];
  }
  red[t] = v;
  __syncthreads();
  for (int off = 64; off >= 1; off >>= 1) {
    if (t < off) red[t] += red[t + off];
    __syncthreads();
  }
  if (t == 0) out[g] = red[0] + bf2[0];
}

extern "C" void kernel_launch(void* const* d_in, const int* in_sizes, int n_in,
                              void* d_out, int out_size, void* d_ws, size_t ws_size,
                              hipStream_t stream) {
  const float* x     = (const float*)d_in[0];
  const int*   ei    = (const int*)d_in[1];
  const int*   batch = (const int*)d_in[2];
  const float* Wl1   = (const float*)d_in[3];
  const float* Wr1   = (const float*)d_in[4];
  const float* att1  = (const float*)d_in[5];
  const float* b1    = (const float*)d_in[6];
  const float* Wl2   = (const float*)d_in[7];
  const float* Wr2   = (const float*)d_in[8];
  const float* att2  = (const float*)d_in[9];
  const float* b2    = (const float*)d_in[10];
  const float* bn_g  = (const float*)d_in[11];
  const float* bn_b  = (const float*)d_in[12];
  const float* bn_rm = (const float*)d_in[13];
  const float* bn_rv = (const float*)d_in[14];
  const float* Wg1   = (const float*)d_in[15];
  const float* bg1   = (const float*)d_in[16];
  const float* Wg2   = (const float*)d_in[17];
  const float* Wf1   = (const float*)d_in[18];
  const float* bf1   = (const float*)d_in[19];
  const float* Wf2   = (const float*)d_in[20];
  const float* bf2   = (const float*)d_in[21];

  const int N  = in_sizes[0] / 128;
  const int E  = in_sizes[1] / 2;
  const int NG = out_size;
  const int* src = ei;
  const int* dst = ei + E;

  // ---- workspace arena (256B-aligned) ----
  char* p = (char*)d_ws;
  auto alloc = [&](size_t bytes) -> void* {
    void* r = (void*)p;
    p += (bytes + 255) & ~(size_t)255;
    return r;
  };
  float* bufA    = (float*)alloc((size_t)N * 128 * 4);  // xl1, later xl2
  float* bufB    = (float*)alloc((size_t)N * 128 * 4);  // xr1, later xr2
  float* h1      = (float*)alloc((size_t)N * 128 * 4);  // h1, later reused as h2
  float* scores  = (float*)alloc((size_t)E * 8 * 4);
  float* mx      = (float*)alloc((size_t)N * 8 * 4);
  int*   deg     = (int*)alloc((size_t)N * 4);
  int*   cursor  = (int*)alloc((size_t)N * 4);
  int*   offs    = (int*)alloc((size_t)N * 4);
  int*   csr_src = (int*)alloc((size_t)E * 4);
  float* gate    = (float*)alloc((size_t)N * 4);
  float* pooled  = (float*)alloc((size_t)NG * 128 * 4);
  float* h2      = h1;  // h1 dead after layer-2 GEMMs; safe alias (in-order stream)

  // ---- CSR build ----
  zero2_kernel<<<(N + 255) / 256, 256, 0, stream>>>(deg, cursor, N);
  hist_kernel<<<1024, 256, 0, stream>>>(dst, E, deg);
  scan_kernel<<<1, 1024, 0, stream>>>(deg, offs, N);
  scatter_kernel<<<1024, 256, 0, stream>>>(src, dst, E, offs, cursor, csr_src);

  // ---- layer 1 ----
  gemm128<<<512, 256, 0, stream>>>(x, Wl1, bufA, N);
  gemm128<<<512, 256, 0, stream>>>(x, Wr1, bufB, N);
  score1_kernel<<<N, 64, 0, stream>>>(bufA, bufB, csr_src, offs, deg, att1, scores, mx, N);
  agg1_kernel<<<N, 64, 0, stream>>>(bufA, csr_src, offs, deg, scores, mx, b1,
                                    bn_g, bn_b, bn_rm, bn_rv, h1, N);

  // ---- layer 2 ----
  gemm128<<<512, 256, 0, stream>>>(h1, Wl2, bufA, N);
  gemm128<<<512, 256, 0, stream>>>(h1, Wr2, bufB, N);
  score2_kernel<<<N, 64, 0, stream>>>(bufA, bufB, csr_src, offs, deg, att2, scores, mx, N);
  agg2_kernel<<<N, 64, 0, stream>>>(bufA, csr_src, offs, deg, scores, mx, b2,
                                    bn_g, bn_b, bn_rm, bn_rv, h2, N);

  // ---- pooling + head ----
  gate_kernel<<<512, 256, 0, stream>>>(h2, Wg1, bg1, Wg2, gate, N);
  pool_kernel<<<NG, 128, 0, stream>>>(gate, h2, batch, N, pooled, NG);
  fc_kernel<<<NG, 128, 0, stream>>>(pooled, Wf1, bf1, Wf2, bf2, (float*)d_out, NG);
}

// Round 3
// 847.830 us; speedup vs baseline: 5.9641x; 1.3502x over previous
//
#include <hip/hip_runtime.h>
#include <math.h>

#define NEG_SLOPE 0.3f
#define BN_EPS 1e-5f

static __device__ __forceinline__ float lrelu(float v) {
  return v >= 0.0f ? v : NEG_SLOPE * v;
}

static __device__ __forceinline__ int lower_bound_i(const int* __restrict__ a, int n, int v) {
  int lo = 0, hi = n;
  while (lo < hi) {
    int mid = (lo + hi) >> 1;
    if (a[mid] < v) lo = mid + 1; else hi = mid;
  }
  return lo;
}

// ---------------- init ----------------
__global__ void zero2_kernel(int* __restrict__ a, int* __restrict__ b, int n) {
  int i = blockIdx.x * blockDim.x + threadIdx.x;
  if (i < n) { a[i] = 0; b[i] = 0; }
}

// ---------------- CSR build ----------------
__global__ void hist_kernel(const int* __restrict__ dst, int ne, int* __restrict__ deg) {
  int i = blockIdx.x * blockDim.x + threadIdx.x;
  int stride = gridDim.x * blockDim.x;
  for (; i < ne; i += stride) atomicAdd(&deg[dst[i]], 1);
}

__global__ __launch_bounds__(1024) void scan_kernel(const int* __restrict__ deg,
    int* __restrict__ offs, int n) {
  __shared__ int part[1024];
  int t = threadIdx.x;
  int chunk = (n + 1023) >> 10;
  int s0 = t * chunk;
  int s1 = min(n, s0 + chunk);
  int sum = 0;
  for (int i = s0; i < s1; ++i) sum += deg[i];
  part[t] = sum;
  __syncthreads();
  for (int off = 1; off < 1024; off <<= 1) {
    int v = (t >= off) ? part[t - off] : 0;
    __syncthreads();
    part[t] += v;
    __syncthreads();
  }
  int run = (t > 0) ? part[t - 1] : 0;
  for (int i = s0; i < s1; ++i) { offs[i] = run; run += deg[i]; }
}

__global__ void scatter_kernel(const int* __restrict__ src, const int* __restrict__ dst,
    int ne, const int* __restrict__ offs, int* __restrict__ cursor,
    int* __restrict__ csr_src) {
  int i = blockIdx.x * blockDim.x + threadIdx.x;
  int stride = gridDim.x * blockDim.x;
  for (; i < ne; i += stride) {
    int d = dst[i];
    int pos = offs[d] + atomicAdd(&cursor[d], 1);
    csr_src[pos] = src[i];
  }
}

// ---------------- GEMM: C[n,128] = A[n,128] @ W[128,128] (fp32) ----------------
// W fully staged in LDS (64 KB). Block = 256 thr = 8 rowgroups x 32 colgroups.
__global__ __launch_bounds__(256) void gemm128(const float* __restrict__ A,
    const float* __restrict__ W, float* __restrict__ C, int n) {
  __shared__ float Wl[128 * 128];  // 64 KB
  int t = threadIdx.x;
  for (int i = t; i < 4096; i += 256)
    ((float4*)Wl)[i] = ((const float4*)W)[i];
  __syncthreads();
  int cg = t & 31;   // colgroup: owns cols 4*cg .. 4*cg+3
  int rg = t >> 5;   // rowgroup: owns 8 rows
  int ntiles = (n + 63) >> 6;
  for (int tile = blockIdx.x; tile < ntiles; tile += gridDim.x) {
    int r0 = (tile << 6) + rg * 8;
    const float* Ar[8];
#pragma unroll
    for (int r = 0; r < 8; ++r) {
      int gr = min(r0 + r, n - 1);          // clamp for loads; stores guarded
      Ar[r] = A + (size_t)gr * 128;
    }
    float4 acc[8];
#pragma unroll
    for (int r = 0; r < 8; ++r) acc[r] = make_float4(0.f, 0.f, 0.f, 0.f);
#pragma unroll 4
    for (int k = 0; k < 128; k += 4) {
      float4 w0 = *(const float4*)&Wl[(k + 0) * 128 + cg * 4];
      float4 w1 = *(const float4*)&Wl[(k + 1) * 128 + cg * 4];
      float4 w2 = *(const float4*)&Wl[(k + 2) * 128 + cg * 4];
      float4 w3 = *(const float4*)&Wl[(k + 3) * 128 + cg * 4];
#pragma unroll
      for (int r = 0; r < 8; ++r) {
        float4 av = *(const float4*)(Ar[r] + k);
        acc[r].x += av.x * w0.x + av.y * w1.x + av.z * w2.x + av.w * w3.x;
        acc[r].y += av.x * w0.y + av.y * w1.y + av.z * w2.y + av.w * w3.y;
        acc[r].z += av.x * w0.z + av.y * w1.z + av.z * w2.z + av.w * w3.z;
        acc[r].w += av.x * w0.w + av.y * w1.w + av.z * w2.w + av.w * w3.w;
      }
    }
#pragma unroll
    for (int r = 0; r < 8; ++r) {
      int gr = r0 + r;
      if (gr < n) *(float4*)&C[(size_t)gr * 128 + cg * 4] = acc[r];
    }
  }
}

// ---------------- gate: gate[n] = tanh(h2 @ Wg1 + bg1) . Wg2 -------------------
__global__ __launch_bounds__(256) void gate_kernel(const float* __restrict__ A,
    const float* __restrict__ Wg1, const float* __restrict__ bg1,
    const float* __restrict__ Wg2, float* __restrict__ gate, int n) {
  __shared__ float Wl[128 * 128];  // 64 KB
  int t = threadIdx.x;
  for (int i = t; i < 4096; i += 256)
    ((float4*)Wl)[i] = ((const float4*)Wg1)[i];
  __syncthreads();
  int cg = t & 31;
  int rg = t >> 5;
  float4 bg4 = *(const float4*)&bg1[cg * 4];
  float4 wg4 = *(const float4*)&Wg2[cg * 4];
  int ntiles = (n + 63) >> 6;
  for (int tile = blockIdx.x; tile < ntiles; tile += gridDim.x) {
    int r0 = (tile << 6) + rg * 8;
    const float* Ar[8];
#pragma unroll
    for (int r = 0; r < 8; ++r) {
      int gr = min(r0 + r, n - 1);
      Ar[r] = A + (size_t)gr * 128;
    }
    float4 acc[8];
#pragma unroll
    for (int r = 0; r < 8; ++r) acc[r] = make_float4(0.f, 0.f, 0.f, 0.f);
#pragma unroll 4
    for (int k = 0; k < 128; k += 4) {
      float4 w0 = *(const float4*)&Wl[(k + 0) * 128 + cg * 4];
      float4 w1 = *(const float4*)&Wl[(k + 1) * 128 + cg * 4];
      float4 w2 = *(const float4*)&Wl[(k + 2) * 128 + cg * 4];
      float4 w3 = *(const float4*)&Wl[(k + 3) * 128 + cg * 4];
#pragma unroll
      for (int r = 0; r < 8; ++r) {
        float4 av = *(const float4*)(Ar[r] + k);
        acc[r].x += av.x * w0.x + av.y * w1.x + av.z * w2.x + av.w * w3.x;
        acc[r].y += av.x * w0.y + av.y * w1.y + av.z * w2.y + av.w * w3.y;
        acc[r].z += av.x * w0.z + av.y * w1.z + av.z * w2.z + av.w * w3.z;
        acc[r].w += av.x * w0.w + av.y * w1.w + av.z * w2.w + av.w * w3.w;
      }
    }
#pragma unroll
    for (int r = 0; r < 8; ++r) {
      float v = tanhf(acc[r].x + bg4.x) * wg4.x
              + tanhf(acc[r].y + bg4.y) * wg4.y
              + tanhf(acc[r].z + bg4.z) * wg4.z
              + tanhf(acc[r].w + bg4.w) * wg4.w;
      v += __shfl_xor(v, 1);
      v += __shfl_xor(v, 2);
      v += __shfl_xor(v, 4);
      v += __shfl_xor(v, 8);
      v += __shfl_xor(v, 16);
      int gr = r0 + r;
      if (cg == 0 && gr < n) gate[gr] = v;
    }
  }
}

// ---------------- GATv2 layer 1 FUSED: online-softmax score+aggregate ----------
// One wave per node. 8 heads x 16ch; lane l owns channels 2l,2l+1; head = l>>3.
// Online softmax: m,s per head (replicated across the head's 8 lanes), rescale
// accumulators when the max moves. Edge loop unrolled x8 for memory parallelism.
__global__ __launch_bounds__(64) void gat1_fused(const float* __restrict__ xl,
    const float* __restrict__ xr, const int* __restrict__ csr_src,
    const int* __restrict__ offs, const int* __restrict__ deg,
    const float* __restrict__ att, const float* __restrict__ bias,
    const float* __restrict__ bn_g, const float* __restrict__ bn_b,
    const float* __restrict__ bn_rm, const float* __restrict__ bn_rv,
    float* __restrict__ out, int n_nodes) {
  int n = blockIdx.x;
  if (n >= n_nodes) return;
  int l = threadIdx.x;
  int base = offs[n], d = deg[n];
  float2 xrv = *(const float2*)&xr[(size_t)n * 128 + 2 * l];
  float a0 = att[2 * l], a1 = att[2 * l + 1];
  float m = -__builtin_inff(), s = 0.f, ax = 0.f, ay = 0.f;

  auto step = [&](float2 xlv) {
    float p = lrelu(xlv.x + xrv.x) * a0 + lrelu(xlv.y + xrv.y) * a1;
    p += __shfl_xor(p, 1);
    p += __shfl_xor(p, 2);
    p += __shfl_xor(p, 4);   // per-head score, replicated in 8 lanes
    float mn = fmaxf(m, p);
    float c = __expf(m - mn);    // m=-inf first time -> c=0
    float ex = __expf(p - mn);
    s = s * c + ex;
    ax = ax * c + ex * xlv.x;
    ay = ay * c + ex * xlv.y;
    m = mn;
  };

  const int* cp = csr_src + base;
  int i = 0;
  for (; i + 8 <= d; i += 8) {
    int e0 = cp[i + 0], e1 = cp[i + 1], e2 = cp[i + 2], e3 = cp[i + 3];
    int e4 = cp[i + 4], e5 = cp[i + 5], e6 = cp[i + 6], e7 = cp[i + 7];
    float2 v0 = *(const float2*)&xl[(size_t)e0 * 128 + 2 * l];
    float2 v1 = *(const float2*)&xl[(size_t)e1 * 128 + 2 * l];
    float2 v2 = *(const float2*)&xl[(size_t)e2 * 128 + 2 * l];
    float2 v3 = *(const float2*)&xl[(size_t)e3 * 128 + 2 * l];
    float2 v4 = *(const float2*)&xl[(size_t)e4 * 128 + 2 * l];
    float2 v5 = *(const float2*)&xl[(size_t)e5 * 128 + 2 * l];
    float2 v6 = *(const float2*)&xl[(size_t)e6 * 128 + 2 * l];
    float2 v7 = *(const float2*)&xl[(size_t)e7 * 128 + 2 * l];
    step(v0); step(v1); step(v2); step(v3);
    step(v4); step(v5); step(v6); step(v7);
  }
  for (; i < d; ++i) {
    int e = cp[i];
    step(*(const float2*)&xl[(size_t)e * 128 + 2 * l]);
  }

  float inv = 1.f / (s + 1e-16f);
  int c0 = 2 * l, c1 = 2 * l + 1;
  float o0 = ax * inv + bias[c0];
  float o1 = ay * inv + bias[c1];
  float sc0 = bn_g[c0] / sqrtf(bn_rv[c0] + BN_EPS);
  float sc1 = bn_g[c1] / sqrtf(bn_rv[c1] + BN_EPS);
  o0 = fmaxf((o0 - bn_rm[c0]) * sc0 + bn_b[c0], 0.f);
  o1 = fmaxf((o1 - bn_rm[c1]) * sc1 + bn_b[c1], 0.f);
  *(float2*)&out[(size_t)n * 128 + 2 * l] = make_float2(o0, o1);
}

// ---------------- GATv2 layer 2 FUSED: 1 head x 128 ch --------------------------
__global__ __launch_bounds__(64) void gat2_fused(const float* __restrict__ xl,
    const float* __restrict__ xr, const int* __restrict__ csr_src,
    const int* __restrict__ offs, const int* __restrict__ deg,
    const float* __restrict__ att, const float* __restrict__ bias,
    const float* __restrict__ bn_g, const float* __restrict__ bn_b,
    const float* __restrict__ bn_rm, const float* __restrict__ bn_rv,
    float* __restrict__ out, int n_nodes) {
  int n = blockIdx.x;
  if (n >= n_nodes) return;
  int l = threadIdx.x;
  int base = offs[n], d = deg[n];
  float2 xrv = *(const float2*)&xr[(size_t)n * 128 + 2 * l];
  float a0 = att[2 * l], a1 = att[2 * l + 1];
  float m = -__builtin_inff(), s = 0.f, ax = 0.f, ay = 0.f;

  auto step = [&](float2 xlv) {
    float p = lrelu(xlv.x + xrv.x) * a0 + lrelu(xlv.y + xrv.y) * a1;
    p += __shfl_xor(p, 1);
    p += __shfl_xor(p, 2);
    p += __shfl_xor(p, 4);
    p += __shfl_xor(p, 8);
    p += __shfl_xor(p, 16);
    p += __shfl_xor(p, 32);  // full-wave score
    float mn = fmaxf(m, p);
    float c = __expf(m - mn);
    float ex = __expf(p - mn);
    s = s * c + ex;
    ax = ax * c + ex * xlv.x;
    ay = ay * c + ex * xlv.y;
    m = mn;
  };

  const int* cp = csr_src + base;
  int i = 0;
  for (; i + 8 <= d; i += 8) {
    int e0 = cp[i + 0], e1 = cp[i + 1], e2 = cp[i + 2], e3 = cp[i + 3];
    int e4 = cp[i + 4], e5 = cp[i + 5], e6 = cp[i + 6], e7 = cp[i + 7];
    float2 v0 = *(const float2*)&xl[(size_t)e0 * 128 + 2 * l];
    float2 v1 = *(const float2*)&xl[(size_t)e1 * 128 + 2 * l];
    float2 v2 = *(const float2*)&xl[(size_t)e2 * 128 + 2 * l];
    float2 v3 = *(const float2*)&xl[(size_t)e3 * 128 + 2 * l];
    float2 v4 = *(const float2*)&xl[(size_t)e4 * 128 + 2 * l];
    float2 v5 = *(const float2*)&xl[(size_t)e5 * 128 + 2 * l];
    float2 v6 = *(const float2*)&xl[(size_t)e6 * 128 + 2 * l];
    float2 v7 = *(const float2*)&xl[(size_t)e7 * 128 + 2 * l];
    step(v0); step(v1); step(v2); step(v3);
    step(v4); step(v5); step(v6); step(v7);
  }
  for (; i < d; ++i) {
    int e = cp[i];
    step(*(const float2*)&xl[(size_t)e * 128 + 2 * l]);
  }

  float inv = 1.f / (s + 1e-16f);
  int c0 = 2 * l, c1 = 2 * l + 1;
  float o0 = ax * inv + bias[c0];
  float o1 = ay * inv + bias[c1];
  float sc0 = bn_g[c0] / sqrtf(bn_rv[c0] + BN_EPS);
  float sc1 = bn_g[c1] / sqrtf(bn_rv[c1] + BN_EPS);
  o0 = fmaxf((o0 - bn_rm[c0]) * sc0 + bn_b[c0], 0.f);
  o1 = fmaxf((o1 - bn_rm[c1]) * sc1 + bn_b[c1], 0.f);
  *(float2*)&out[(size_t)n * 128 + 2 * l] = make_float2(o0, o1);
}

// ---------------- attentional pooling per graph ----------------
__global__ __launch_bounds__(128) void pool_kernel(const float* __restrict__ gate,
    const float* __restrict__ h2, const int* __restrict__ batch, int n_nodes,
    float* __restrict__ pooled, int n_graphs) {
  int g = blockIdx.x;
  if (g >= n_graphs) return;
  int t = threadIdx.x;
  int start = lower_bound_i(batch, n_nodes, g);
  int end = lower_bound_i(batch, n_nodes, g + 1);
  __shared__ float red[128];
  float m = -__builtin_inff();
  for (int i = start + t; i < end; i += 128) m = fmaxf(m, gate[i]);
  red[t] = m;
  __syncthreads();
  for (int off = 64; off >= 1; off >>= 1) {
    if (t < off) red[t] = fmaxf(red[t], red[t + off]);
    __syncthreads();
  }
  m = red[0];
  float s = 0.f, acc = 0.f;
  for (int i = start; i < end; ++i) {
    float ex = __expf(gate[i] - m);
    s += ex;
    acc += ex * h2[(size_t)i * 128 + t];
  }
  pooled[(size_t)g * 128 + t] = acc / (s + 1e-16f);
}

// ---------------- fc head: out = relu(pooled @ Wf1 + bf1) @ Wf2 + bf2 ----------
__global__ __launch_bounds__(128) void fc_kernel(const float* __restrict__ pooled,
    const float* __restrict__ Wf1, const float* __restrict__ bf1,
    const float* __restrict__ Wf2, const float* __restrict__ bf2,
    float* __restrict__ out, int n_graphs) {
  int g = blockIdx.x;
  if (g >= n_graphs) return;
  int t = threadIdx.x;
  __shared__ float pl[128];
  __shared__ float red[128];
  pl[t] = pooled[(size_t)g * 128 + t];
  __syncthreads();
  float v = 0.f;
  if (t < 100) {
    float acc = bf1[t];
    for (int k = 0; k < 128; ++k) acc += pl[k] * Wf1[k * 100 + t];
    v = fmaxf(acc, 0.f) * Wf2[t];
  }
  red[t] = v;
  __syncthreads();
  for (int off = 64; off >= 1; off >>= 1) {
    if (t < off) red[t] += red[t + off];
    __syncthreads();
  }
  if (t == 0) out[g] = red[0] + bf2[0];
}

extern "C" void kernel_launch(void* const* d_in, const int* in_sizes, int n_in,
                              void* d_out, int out_size, void* d_ws, size_t ws_size,
                              hipStream_t stream) {
  const float* x     = (const float*)d_in[0];
  const int*   ei    = (const int*)d_in[1];
  const int*   batch = (const int*)d_in[2];
  const float* Wl1   = (const float*)d_in[3];
  const float* Wr1   = (const float*)d_in[4];
  const float* att1  = (const float*)d_in[5];
  const float* b1    = (const float*)d_in[6];
  const float* Wl2   = (const float*)d_in[7];
  const float* Wr2   = (const float*)d_in[8];
  const float* att2  = (const float*)d_in[9];
  const float* b2    = (const float*)d_in[10];
  const float* bn_g  = (const float*)d_in[11];
  const float* bn_b  = (const float*)d_in[12];
  const float* bn_rm = (const float*)d_in[13];
  const float* bn_rv = (const float*)d_in[14];
  const float* Wg1   = (const float*)d_in[15];
  const float* bg1   = (const float*)d_in[16];
  const float* Wg2   = (const float*)d_in[17];
  const float* Wf1   = (const float*)d_in[18];
  const float* bf1   = (const float*)d_in[19];
  const float* Wf2   = (const float*)d_in[20];
  const float* bf2   = (const float*)d_in[21];

  const int N  = in_sizes[0] / 128;
  const int E  = in_sizes[1] / 2;
  const int NG = out_size;
  const int* src = ei;
  const int* dst = ei + E;

  // ---- workspace arena (256B-aligned) ----
  char* p = (char*)d_ws;
  auto alloc = [&](size_t bytes) -> void* {
    void* r = (void*)p;
    p += (bytes + 255) & ~(size_t)255;
    return r;
  };
  float* bufA    = (float*)alloc((size_t)N * 128 * 4);  // xl1, later xl2
  float* bufB    = (float*)alloc((size_t)N * 128 * 4);  // xr1, later xr2
  float* h1      = (float*)alloc((size_t)N * 128 * 4);  // h1, later reused as h2
  int*   deg     = (int*)alloc((size_t)N * 4);
  int*   cursor  = (int*)alloc((size_t)N * 4);
  int*   offs    = (int*)alloc((size_t)N * 4);
  int*   csr_src = (int*)alloc((size_t)E * 4);
  float* gate    = (float*)alloc((size_t)N * 4);
  float* pooled  = (float*)alloc((size_t)NG * 128 * 4);
  float* h2      = h1;  // h1 dead after layer-2 GEMMs; safe alias (in-order stream)

  // ---- CSR build ----
  zero2_kernel<<<(N + 255) / 256, 256, 0, stream>>>(deg, cursor, N);
  hist_kernel<<<1024, 256, 0, stream>>>(dst, E, deg);
  scan_kernel<<<1, 1024, 0, stream>>>(deg, offs, N);
  scatter_kernel<<<1024, 256, 0, stream>>>(src, dst, E, offs, cursor, csr_src);

  // ---- layer 1 ----
  gemm128<<<512, 256, 0, stream>>>(x, Wl1, bufA, N);
  gemm128<<<512, 256, 0, stream>>>(x, Wr1, bufB, N);
  gat1_fused<<<N, 64, 0, stream>>>(bufA, bufB, csr_src, offs, deg, att1, b1,
                                   bn_g, bn_b, bn_rm, bn_rv, h1, N);

  // ---- layer 2 ----
  gemm128<<<512, 256, 0, stream>>>(h1, Wl2, bufA, N);
  gemm128<<<512, 256, 0, stream>>>(h1, Wr2, bufB, N);
  gat2_fused<<<N, 64, 0, stream>>>(bufA, bufB, csr_src, offs, deg, att2, b2,
                                   bn_g, bn_b, bn_rm, bn_rv, h2, N);

  // ---- pooling + head ----
  gate_kernel<<<512, 256, 0, stream>>>(h2, Wg1, bg1, Wg2, gate, N);
  pool_kernel<<<NG, 128, 0, stream>>>(gate, h2, batch, N, pooled, NG);
  fc_kernel<<<NG, 128, 0, stream>>>(pooled, Wf1, bf1, Wf2, bf2, (float*)d_out, NG);
}